// Round 2
// baseline (484.920 us; speedup 1.0000x reference)
//
#include <hip/hip_runtime.h>
#include <math.h>

#define NN 20000
#define EE 320000
#define ETOT 340000
#define GG 64
#define INCH 128
#define HIDC 64
#define NH 8
#define HC 512            // NH*HIDC
#define SLOPE 0.2f
#define SMEPS 1e-16f
#define NEG_INF (-3.402823466e38f)

// ---------------- CSR build ----------------
__global__ void k_hist(const int* __restrict__ ei, int* __restrict__ deg) {
  int i = blockIdx.x * 256 + threadIdx.x;
  if (i >= ETOT) return;
  int d = (i < EE) ? ei[EE + i] : (i - EE);
  atomicAdd(&deg[d], 1);
}

__global__ void k_scan(const int* __restrict__ deg, int* __restrict__ rowstart) {
  __shared__ int wsum[16];
  __shared__ int carry_sh;
  int tid = threadIdx.x;
  int lane = tid & 63, w = tid >> 6;
  if (tid == 0) { carry_sh = 0; rowstart[0] = 0; }
  __syncthreads();
  for (int base = 0; base < NN; base += 1024) {
    int v = (base + tid < NN) ? deg[base + tid] : 0;
    int s = v;
#pragma unroll
    for (int off = 1; off < 64; off <<= 1) {
      int t = __shfl_up(s, off);
      if (lane >= off) s += t;
    }
    if (lane == 63) wsum[w] = s;
    __syncthreads();
    if (w == 0 && lane < 16) {
      int t = wsum[lane];
#pragma unroll
      for (int off = 1; off < 16; off <<= 1) {
        int u = __shfl_up(t, off);
        if (lane >= off) t += u;
      }
      wsum[lane] = t;
    }
    __syncthreads();
    int waveoff = (w == 0) ? 0 : wsum[w - 1];
    int incl = s + waveoff + carry_sh;
    if (base + tid < NN) rowstart[base + tid + 1] = incl;
    __syncthreads();
    if (tid == 1023) carry_sh = incl;
    __syncthreads();
  }
}

__global__ void k_fill(const int* __restrict__ ei, const int* __restrict__ rowstart,
                       int* __restrict__ wcur, int* __restrict__ csr) {
  int i = blockIdx.x * 256 + threadIdx.x;
  if (i >= ETOT) return;
  int s, d;
  if (i < EE) { s = ei[i]; d = ei[EE + i]; } else { s = i - EE; d = s; }
  int pos = rowstart[d] + atomicAdd(&wcur[d], 1);
  csr[pos] = s;
}

// ---------------- weight pre-transpose ----------------
// W1 [512][128] -> W1T [128][512];  W2 [64][512] -> W2T [512][64]
__global__ void k_transW(const float* __restrict__ W1, const float* __restrict__ W2,
                         float* __restrict__ W1T, float* __restrict__ W2T) {
  int i = blockIdx.x * 256 + threadIdx.x;
  if (i < 512 * 128) {
    int k = i >> 9, o = i & 511;
    W1T[i] = W1[o * 128 + k];
  } else {
    int j = i - 512 * 128;
    if (j < 512 * 64) {
      int k = j >> 6, c = j & 63;
      W2T[j] = W2[c * 512 + k];
    }
  }
}

// ---------------- GEMM1: h1 = x @ W1^T (col-slice blocks, W-in-LDS-once) ----------------
#define G1_RPW 16
__global__ __launch_bounds__(256) void k_gemm1(
    const float* __restrict__ x, const float* __restrict__ W1T,
    const float* __restrict__ att_s, const float* __restrict__ att_d,
    float* __restrict__ h1, float* __restrict__ as1, float* __restrict__ ad1) {
  __shared__ float ws[128][64];   // 32 KB; W slice for cols [slice*64, slice*64+64)
  int tid = threadIdx.x;
  int lane = tid & 63, wv = tid >> 6;
  int slice = blockIdx.x & 7;           // == head index
  int mblk = blockIdx.x >> 3;

  {
    int cc4 = (tid & 15) * 4;
    int k0 = tid >> 4;                  // 0..15
#pragma unroll
    for (int p = 0; p < 8; ++p) {
      int k = k0 + p * 16;
      *(float4*)&ws[k][cc4] = *(const float4*)(W1T + (size_t)k * HC + slice * 64 + cc4);
    }
  }
  __syncthreads();

  int row0 = mblk * 64 + wv * G1_RPW;
  if (row0 > NN - G1_RPW) row0 = NN - G1_RPW;   // tail clamp: duplicate identical work
  row0 = __builtin_amdgcn_readfirstlane(row0);
  const float* xp = x + (size_t)row0 * INCH;

  float acc[G1_RPW];
#pragma unroll
  for (int r = 0; r < G1_RPW; ++r) acc[r] = 0.f;

#pragma unroll 2
  for (int kc = 0; kc < 32; ++kc) {
    float wvv[4];
#pragma unroll
    for (int q = 0; q < 4; ++q) wvv[q] = ws[kc * 4 + q][lane];
#pragma unroll
    for (int r = 0; r < G1_RPW; ++r) {
      const float4 xv = *(const float4*)(xp + r * INCH + kc * 4);
      acc[r] = fmaf(xv.x, wvv[0], acc[r]);
      acc[r] = fmaf(xv.y, wvv[1], acc[r]);
      acc[r] = fmaf(xv.z, wvv[2], acc[r]);
      acc[r] = fmaf(xv.w, wvv[3], acc[r]);
    }
  }

  int c = slice * 64 + lane;
  float asw = att_s[c], adw = att_d[c];
#pragma unroll
  for (int r = 0; r < G1_RPW; ++r) {
    int n = row0 + r;
    h1[(size_t)n * HC + c] = acc[r];
    float ps = acc[r] * asw, pd = acc[r] * adw;
#pragma unroll
    for (int off = 32; off; off >>= 1) {
      ps += __shfl_xor(ps, off);
      pd += __shfl_xor(pd, off);
    }
    if (lane == 0) { as1[(size_t)n * NH + slice] = ps; ad1[(size_t)n * NH + slice] = pd; }
  }
}

// ---------------- GEMM2: h2 = xmid @ W2^T (64 cols, K=512 in 4 LDS windows) ----------------
#define G2_RPW 16
__global__ __launch_bounds__(128) void k_gemm2(
    const float* __restrict__ xm, const float* __restrict__ W2T,
    const float* __restrict__ att_s, const float* __restrict__ att_d,
    float* __restrict__ h2, float* __restrict__ as2, float* __restrict__ ad2) {
  __shared__ float ws[128][64];   // 32 KB window: k in [w*128, w*128+128)
  int tid = threadIdx.x;
  int lane = tid & 63, wv = tid >> 6;
  int row0 = blockIdx.x * 32 + wv * G2_RPW;     // 625 blocks exact
  row0 = __builtin_amdgcn_readfirstlane(row0);
  const float* xp = xm + (size_t)row0 * HC;

  float acc[G2_RPW];
#pragma unroll
  for (int r = 0; r < G2_RPW; ++r) acc[r] = 0.f;

  for (int w = 0; w < 4; ++w) {
    __syncthreads();
    {
      int cc4 = (tid & 15) * 4;
      int k0 = tid >> 4;                // 0..7
#pragma unroll
      for (int p = 0; p < 16; ++p) {
        int k = k0 + p * 8;
        *(float4*)&ws[k][cc4] = *(const float4*)(W2T + (size_t)(w * 128 + k) * 64 + cc4);
      }
    }
    __syncthreads();
#pragma unroll 2
    for (int kc = 0; kc < 32; ++kc) {
      float wvv[4];
#pragma unroll
      for (int q = 0; q < 4; ++q) wvv[q] = ws[kc * 4 + q][lane];
#pragma unroll
      for (int r = 0; r < G2_RPW; ++r) {
        const float4 xv = *(const float4*)(xp + r * HC + w * 128 + kc * 4);
        acc[r] = fmaf(xv.x, wvv[0], acc[r]);
        acc[r] = fmaf(xv.y, wvv[1], acc[r]);
        acc[r] = fmaf(xv.z, wvv[2], acc[r]);
        acc[r] = fmaf(xv.w, wvv[3], acc[r]);
      }
    }
  }

  float asw = att_s[lane], adw = att_d[lane];
#pragma unroll
  for (int r = 0; r < G2_RPW; ++r) {
    int n = row0 + r;
    h2[(size_t)n * HIDC + lane] = acc[r];
    float ps = acc[r] * asw, pd = acc[r] * adw;
#pragma unroll
    for (int off = 32; off; off >>= 1) {
      ps += __shfl_xor(ps, off);
      pd += __shfl_xor(pd, off);
    }
    if (lane == 0) { as2[n] = ps; ad2[n] = pd; }
  }
}

// ---------------- Layer-1 fused softmax + aggregate (block per node) ----------------
#define CH1 256
__global__ __launch_bounds__(256) void k_node1(
    const float* __restrict__ h1, const float* __restrict__ as1, const float* __restrict__ ad1,
    const int* __restrict__ rowstart, const int* __restrict__ csr,
    const float* __restrict__ b1, float* __restrict__ xmid) {
  int n = blockIdx.x;
  int tid = threadIdx.x;
  int rs = rowstart[n], re = rowstart[n + 1];
  __shared__ float e_lds[CH1][NH + 1];
  __shared__ int s_sh[CH1];
  __shared__ float ad_sh[NH], m_sh[NH], z_sh[NH], f_sh[NH], c_sh[NH];
  if (tid < NH) { ad_sh[tid] = ad1[(size_t)n * NH + tid]; m_sh[tid] = NEG_INF; z_sh[tid] = 0.f; }
  __syncthreads();
  int myh = tid >> 5;
  int lane32 = tid & 31;
  int c0 = tid * 2;
  float accx = 0.f, accy = 0.f;

  for (int base = rs; base < re; base += CH1) {
    int cn = min(CH1, re - base);
    if (tid < cn) {
      int s = csr[base + tid];
      s_sh[tid] = s;
      const float4 a0 = *(const float4*)(as1 + (size_t)s * NH);
      const float4 a1 = *(const float4*)(as1 + (size_t)s * NH + 4);
      float ev[8] = {a0.x + ad_sh[0], a0.y + ad_sh[1], a0.z + ad_sh[2], a0.w + ad_sh[3],
                     a1.x + ad_sh[4], a1.y + ad_sh[5], a1.z + ad_sh[6], a1.w + ad_sh[7]};
#pragma unroll
      for (int h = 0; h < NH; ++h) {
        float e = ev[h];
        e_lds[tid][h] = (e > 0.f) ? e : SLOPE * e;
      }
    }
    __syncthreads();
    float mv = NEG_INF;
    for (int j = lane32; j < cn; j += 32) mv = fmaxf(mv, e_lds[j][myh]);
#pragma unroll
    for (int off = 16; off; off >>= 1) mv = fmaxf(mv, __shfl_xor(mv, off));
    if (lane32 == 0) c_sh[myh] = mv;
    __syncthreads();
    if (tid < NH) {
      float mo = m_sh[tid];
      float mn = fmaxf(mo, c_sh[tid]);
      float f = (mo <= NEG_INF) ? 0.f : __expf(mo - mn);
      f_sh[tid] = f; m_sh[tid] = mn; z_sh[tid] *= f;
    }
    __syncthreads();
    float mn = m_sh[myh];
    float zs = 0.f;
    for (int j = lane32; j < cn; j += 32) {
      float p = __expf(e_lds[j][myh] - mn);
      e_lds[j][myh] = p;
      zs += p;
    }
#pragma unroll
    for (int off = 16; off; off >>= 1) zs += __shfl_xor(zs, off);
    float f = f_sh[myh];
    accx *= f; accy *= f;
    if (lane32 == 0) z_sh[myh] += zs;
    __syncthreads();
    for (int j = 0; j < cn; ++j) {
      float p = e_lds[j][myh];
      const float2 hv = *(const float2*)(h1 + (size_t)s_sh[j] * HC + c0);
      accx = fmaf(p, hv.x, accx);
      accy = fmaf(p, hv.y, accy);
    }
    __syncthreads();
  }
  float inv = 1.f / (z_sh[myh] + SMEPS);
  float vx = fmaxf(accx * inv + b1[c0], 0.f);
  float vy = fmaxf(accy * inv + b1[c0 + 1], 0.f);
  float2 o2; o2.x = vx; o2.y = vy;
  *(float2*)(xmid + (size_t)n * HC + c0) = o2;
}

// ---------------- Layer-2 fused softmax + aggregate (wave per node, shfl-based) ----------------
__global__ __launch_bounds__(256) void k_node2(
    const float* __restrict__ h2, const float* __restrict__ as2, const float* __restrict__ ad2,
    const int* __restrict__ rowstart, const int* __restrict__ csr,
    const float* __restrict__ b2, float* __restrict__ out) {
  int n = blockIdx.x * 4 + (threadIdx.x >> 6);
  if (n >= NN) return;
  int lane = threadIdx.x & 63;
  int rs = rowstart[n], re = rowstart[n + 1];
  float ad = ad2[n];
  float m = NEG_INF, z = 0.f, acc = 0.f;
  for (int base = rs; base < re; base += 64) {
    int cn = min(64, re - base);
    float e = NEG_INF;
    int s = 0;
    if (lane < cn) {
      s = csr[base + lane];
      float t = as2[s] + ad;
      e = (t > 0.f) ? t : SLOPE * t;
    }
    float cm = e;
#pragma unroll
    for (int off = 32; off; off >>= 1) cm = fmaxf(cm, __shfl_xor(cm, off));
    float mn = fmaxf(m, cm);
    float f = (m <= NEG_INF) ? 0.f : __expf(m - mn);
    float p = (lane < cn) ? __expf(e - mn) : 0.f;
    float zc = p;
#pragma unroll
    for (int off = 32; off; off >>= 1) zc += __shfl_xor(zc, off);
    z = z * f + zc;
    acc *= f;
    m = mn;
    for (int j = 0; j < cn; ++j) {
      float pj = __shfl(p, j);
      int sj = __shfl(s, j);
      acc = fmaf(pj, h2[(size_t)sj * HIDC + lane], acc);
    }
  }
  out[(size_t)n * HIDC + lane] = acc / (z + SMEPS) + b2[lane];
}

// ---------------- mean pool (block per graph; batch is sorted) ----------------
__device__ inline int lowerb(const int* a, int n, int v) {
  int lo = 0, hi = n;
  while (lo < hi) { int mid = (lo + hi) >> 1; if (a[mid] < v) lo = mid + 1; else hi = mid; }
  return lo;
}

__global__ __launch_bounds__(256) void k_pool(const float* __restrict__ xm,
                                              const int* __restrict__ batch,
                                              float* __restrict__ out) {
  int g = blockIdx.x;
  int tid = threadIdx.x;
  int lo = lowerb(batch, NN, g);
  int hi = lowerb(batch, NN, g + 1);
  float inv = 1.f / fmaxf((float)(hi - lo), 1.f);
  int c = tid * 2;
  float sx = 0.f, sy = 0.f;
  int n = lo;
  for (; n + 4 <= hi; n += 4) {
    float2 v0 = *(const float2*)(xm + (size_t)(n + 0) * HC + c);
    float2 v1 = *(const float2*)(xm + (size_t)(n + 1) * HC + c);
    float2 v2 = *(const float2*)(xm + (size_t)(n + 2) * HC + c);
    float2 v3 = *(const float2*)(xm + (size_t)(n + 3) * HC + c);
    sx += (v0.x + v1.x) + (v2.x + v3.x);
    sy += (v0.y + v1.y) + (v2.y + v3.y);
  }
  for (; n < hi; ++n) {
    float2 v = *(const float2*)(xm + (size_t)n * HC + c);
    sx += v.x; sy += v.y;
  }
  out[(size_t)g * HC + c] = sx * inv;
  out[(size_t)g * HC + c + 1] = sy * inv;
}

extern "C" void kernel_launch(void* const* d_in, const int* in_sizes, int n_in,
                              void* d_out, int out_size, void* d_ws, size_t ws_size,
                              hipStream_t stream) {
  const float* x     = (const float*)d_in[0];
  const int*   ei    = (const int*)d_in[1];
  const int*   batch = (const int*)d_in[2];
  const float* W1    = (const float*)d_in[3];
  const float* atts1 = (const float*)d_in[4];
  const float* attd1 = (const float*)d_in[5];
  const float* b1    = (const float*)d_in[6];
  const float* W2    = (const float*)d_in[7];
  const float* atts2 = (const float*)d_in[8];
  const float* attd2 = (const float*)d_in[9];
  const float* b2    = (const float*)d_in[10];
  float* out = (float*)d_out;

  float* ws = (float*)d_ws;
  size_t off = 0;
  float* h1   = ws + off; off += (size_t)NN * HC;
  float* xmid = ws + off; off += (size_t)NN * HC;
  float* h2   = ws + off; off += (size_t)NN * HIDC;
  float* as1  = ws + off; off += (size_t)NN * NH;
  float* ad1  = ws + off; off += (size_t)NN * NH;
  float* as2  = ws + off; off += NN;
  float* ad2  = ws + off; off += NN;
  float* W1T  = ws + off; off += 512 * 128;
  float* W2T  = ws + off; off += 512 * 64;
  int* deg      = (int*)(ws + off); off += NN;
  int* wcur     = (int*)(ws + off); off += NN;
  int* rowstart = (int*)(ws + off); off += NN + 4;
  int* csr      = (int*)(ws + off); off += ETOT;

  hipMemsetAsync(deg, 0, sizeof(int) * 2 * NN, stream);
  k_transW<<<384, 256, 0, stream>>>(W1, W2, W1T, W2T);
  k_hist<<<(ETOT + 255) / 256, 256, 0, stream>>>(ei, deg);
  k_scan<<<1, 1024, 0, stream>>>(deg, rowstart);
  k_fill<<<(ETOT + 255) / 256, 256, 0, stream>>>(ei, rowstart, wcur, csr);

  k_gemm1<<<313 * 8, 256, 0, stream>>>(x, W1T, atts1, attd1, h1, as1, ad1);
  k_node1<<<NN, 256, 0, stream>>>(h1, as1, ad1, rowstart, csr, b1, xmid);
  k_pool<<<GG, 256, 0, stream>>>(xmid, batch, out);
  k_gemm2<<<625, 128, 0, stream>>>(xmid, W2T, atts2, attd2, h2, as2, ad2);
  k_node2<<<5000, 256, 0, stream>>>(h2, as2, ad2, rowstart, csr, b2, out + (size_t)GG * HC);
}

// Round 3
// 440.964 us; speedup vs baseline: 1.0997x; 1.0997x over previous
//
#include <hip/hip_runtime.h>
#include <math.h>

#define NN 20000
#define EE 320000
#define ETOT 340000
#define GG 64
#define INCH 128
#define HIDC 64
#define NH 8
#define HC 512            // NH*HIDC
#define SLOPE 0.2f
#define SMEPS 1e-16f
#define NEG_INF (-3.402823466e38f)
#define KW 32

// ---------------- CSR build ----------------
__global__ void k_hist(const int* __restrict__ ei, int* __restrict__ deg) {
  int i = blockIdx.x * 256 + threadIdx.x;
  if (i >= ETOT) return;
  int d = (i < EE) ? ei[EE + i] : (i - EE);
  atomicAdd(&deg[d], 1);
}

__global__ void k_scan(const int* __restrict__ deg, int* __restrict__ rowstart) {
  __shared__ int wsum[16];
  __shared__ int carry_sh;
  int tid = threadIdx.x;
  int lane = tid & 63, w = tid >> 6;
  if (tid == 0) { carry_sh = 0; rowstart[0] = 0; }
  __syncthreads();
  for (int base = 0; base < NN; base += 1024) {
    int v = (base + tid < NN) ? deg[base + tid] : 0;
    int s = v;
#pragma unroll
    for (int off = 1; off < 64; off <<= 1) {
      int t = __shfl_up(s, off);
      if (lane >= off) s += t;
    }
    if (lane == 63) wsum[w] = s;
    __syncthreads();
    if (w == 0 && lane < 16) {
      int t = wsum[lane];
#pragma unroll
      for (int off = 1; off < 16; off <<= 1) {
        int u = __shfl_up(t, off);
        if (lane >= off) t += u;
      }
      wsum[lane] = t;
    }
    __syncthreads();
    int waveoff = (w == 0) ? 0 : wsum[w - 1];
    int incl = s + waveoff + carry_sh;
    if (base + tid < NN) rowstart[base + tid + 1] = incl;
    __syncthreads();
    if (tid == 1023) carry_sh = incl;
    __syncthreads();
  }
}

__global__ void k_fill(const int* __restrict__ ei, const int* __restrict__ rowstart,
                       int* __restrict__ wcur, int* __restrict__ csr) {
  int i = blockIdx.x * 256 + threadIdx.x;
  if (i >= ETOT) return;
  int s, d;
  if (i < EE) { s = ei[i]; d = ei[EE + i]; } else { s = i - EE; d = s; }
  int pos = rowstart[d] + atomicAdd(&wcur[d], 1);
  csr[pos] = s;
}

// ---------------- weight prep: W1T[128][512], W2T[512][64], wB1[128][16] ----------------
__global__ void k_prep(const float* __restrict__ W1, const float* __restrict__ W2,
                       const float* __restrict__ as1, const float* __restrict__ ad1v,
                       float* __restrict__ W1T, float* __restrict__ W2T,
                       float* __restrict__ wB1) {
  int i = blockIdx.x * 256 + threadIdx.x;
  if (i < 512 * 128) {
    int k = i >> 9, o = i & 511;
    W1T[i] = W1[o * 128 + k];
  } else if (i < 512 * 128 + 512 * 64) {
    int j = i - 512 * 128;
    int k = j >> 6, c = j & 63;
    W2T[j] = W2[c * 512 + k];
  } else if (i < 512 * 128 + 512 * 64 + 2048) {
    int j = i - 512 * 128 - 512 * 64;   // j = k*16 + c
    int k = j >> 4, c = j & 15;
    int h = c & 7;
    const float* av = (c < 8) ? as1 : ad1v;
    float s = 0.f;
    for (int q = 0; q < 64; ++q) s += W1[(h * 64 + q) * 128 + k] * av[h * 64 + q];
    wB1[j] = s;
  }
}

// ---------------- logits1: al1[n][0..7]=x@wS, [8..15]=x@wD ----------------
__global__ __launch_bounds__(256) void k_logits1(
    const float* __restrict__ x, const float* __restrict__ wB1,
    float* __restrict__ al1) {
  __shared__ float As[256 * 33];
  int tid = threadIdx.x;
  int lane = tid & 63, wv = tid >> 6;
  int n0 = blockIdx.x * 256;
  int lrow = wv * 64 + lane;
  int myrow = n0 + lrow; if (myrow > NN - 1) myrow = NN - 1;

  float acc[16];
#pragma unroll
  for (int c = 0; c < 16; ++c) acc[c] = 0.f;

  float4 st[8];
  int sr[8], sk[8];
#pragma unroll
  for (int p = 0; p < 8; ++p) {
    int i = tid + p * 256;
    sr[p] = i >> 3; sk[p] = (i & 7) * 4;
    int gr = n0 + sr[p]; if (gr > NN - 1) gr = NN - 1;
    st[p] = *(const float4*)(x + (size_t)gr * INCH + sk[p]);
  }
  for (int kw = 0; kw < INCH / KW; ++kw) {
#pragma unroll
    for (int p = 0; p < 8; ++p) {
      int base = sr[p] * 33 + sk[p];
      As[base + 0] = st[p].x; As[base + 1] = st[p].y;
      As[base + 2] = st[p].z; As[base + 3] = st[p].w;
    }
    __syncthreads();
    if (kw + 1 < INCH / KW) {
#pragma unroll
      for (int p = 0; p < 8; ++p) {
        int gr = n0 + sr[p]; if (gr > NN - 1) gr = NN - 1;
        st[p] = *(const float4*)(x + (size_t)gr * INCH + (kw + 1) * KW + sk[p]);
      }
    }
    const float* Wk = wB1 + kw * KW * 16;
#pragma unroll 4
    for (int kk = 0; kk < KW; ++kk) {
      float a = As[lrow * 33 + kk];
      const float* wr = Wk + kk * 16;
#pragma unroll
      for (int c = 0; c < 16; ++c) acc[c] = fmaf(a, wr[c], acc[c]);
    }
    __syncthreads();
  }
  float* op = al1 + (size_t)myrow * 16;
#pragma unroll
  for (int c4 = 0; c4 < 4; ++c4) {
    float4 o; o.x = acc[c4 * 4]; o.y = acc[c4 * 4 + 1]; o.z = acc[c4 * 4 + 2]; o.w = acc[c4 * 4 + 3];
    *(float4*)(op + c4 * 4) = o;
  }
}

// ---------------- agg1: per-node softmax over edges (8 heads), aggregate x ----------------
#define CH1 256
__global__ __launch_bounds__(256) void k_agg1(
    const float* __restrict__ x, const float* __restrict__ al1,
    const int* __restrict__ rowstart, const int* __restrict__ csr,
    float* __restrict__ agg) {
  int n = blockIdx.x;
  int tid = threadIdx.x;
  int rs = rowstart[n], re = rowstart[n + 1];
  __shared__ float e_lds[CH1][NH + 1];
  __shared__ int s_sh[CH1];
  __shared__ float ad_sh[NH], m_sh[NH], z_sh[NH], f_sh[NH], c_sh[NH];
  if (tid < NH) { ad_sh[tid] = al1[(size_t)n * 16 + 8 + tid]; m_sh[tid] = NEG_INF; z_sh[tid] = 0.f; }
  __syncthreads();
  int myh = tid >> 5;
  int lane32 = tid & 31;
  int k0 = lane32 * 4;
  float ax = 0.f, ay = 0.f, az = 0.f, aw = 0.f;

  for (int base = rs; base < re; base += CH1) {
    int cn = min(CH1, re - base);
    if (tid < cn) {
      int s = csr[base + tid];
      s_sh[tid] = s;
      const float4 a0 = *(const float4*)(al1 + (size_t)s * 16);
      const float4 a1 = *(const float4*)(al1 + (size_t)s * 16 + 4);
      float ev[8] = {a0.x + ad_sh[0], a0.y + ad_sh[1], a0.z + ad_sh[2], a0.w + ad_sh[3],
                     a1.x + ad_sh[4], a1.y + ad_sh[5], a1.z + ad_sh[6], a1.w + ad_sh[7]};
#pragma unroll
      for (int h = 0; h < NH; ++h) {
        float e = ev[h];
        e_lds[tid][h] = (e > 0.f) ? e : SLOPE * e;
      }
    }
    __syncthreads();
    float mv = NEG_INF;
    for (int j = lane32; j < cn; j += 32) mv = fmaxf(mv, e_lds[j][myh]);
#pragma unroll
    for (int off = 16; off; off >>= 1) mv = fmaxf(mv, __shfl_xor(mv, off));
    if (lane32 == 0) c_sh[myh] = mv;
    __syncthreads();
    if (tid < NH) {
      float mo = m_sh[tid];
      float mn = fmaxf(mo, c_sh[tid]);
      float f = (mo <= NEG_INF) ? 0.f : __expf(mo - mn);
      f_sh[tid] = f; m_sh[tid] = mn; z_sh[tid] *= f;
    }
    __syncthreads();
    float mn = m_sh[myh];
    float zs = 0.f;
    for (int j = lane32; j < cn; j += 32) {
      float p = __expf(e_lds[j][myh] - mn);
      e_lds[j][myh] = p;
      zs += p;
    }
#pragma unroll
    for (int off = 16; off; off >>= 1) zs += __shfl_xor(zs, off);
    float f = f_sh[myh];
    ax *= f; ay *= f; az *= f; aw *= f;
    if (lane32 == 0) z_sh[myh] += zs;
    __syncthreads();
#pragma unroll 2
    for (int j = 0; j < cn; ++j) {
      float p = e_lds[j][myh];
      const float4 xv = *(const float4*)(x + (size_t)s_sh[j] * INCH + k0);
      ax = fmaf(p, xv.x, ax); ay = fmaf(p, xv.y, ay);
      az = fmaf(p, xv.z, az); aw = fmaf(p, xv.w, aw);
    }
    __syncthreads();
  }
  float inv = 1.f / (z_sh[myh] + SMEPS);
  float4 o; o.x = ax * inv; o.y = ay * inv; o.z = az * inv; o.w = aw * inv;
  *(float4*)(agg + (size_t)myh * NN * INCH + (size_t)n * INCH + k0) = o;
}

// ---------------- gemm1h: xmid[n][h*64+c] = relu(agg_h[n]@W1T[:,h*64+c] + b1) ----------------
__global__ __launch_bounds__(256) void k_gemm1h(
    const float* __restrict__ agg, const float* __restrict__ W1T,
    const float* __restrict__ b1, float* __restrict__ xmid) {
  __shared__ float As[256 * 33];
  int tid = threadIdx.x;
  int lane = tid & 63, wv = tid >> 6;
  int head = blockIdx.x & 7;
  int n0 = (blockIdx.x >> 3) * 256;
  const float* Ab = agg + (size_t)head * NN * INCH;
  int col0 = head * 64;
  int lrow = wv * 64 + lane;
  int myrow = n0 + lrow; if (myrow > NN - 1) myrow = NN - 1;

  float acc[64];
#pragma unroll
  for (int c = 0; c < 64; ++c) acc[c] = 0.f;

  float4 st[8];
  int sr[8], sk[8];
#pragma unroll
  for (int p = 0; p < 8; ++p) {
    int i = tid + p * 256;
    sr[p] = i >> 3; sk[p] = (i & 7) * 4;
    int gr = n0 + sr[p]; if (gr > NN - 1) gr = NN - 1;
    st[p] = *(const float4*)(Ab + (size_t)gr * INCH + sk[p]);
  }
  for (int kw = 0; kw < INCH / KW; ++kw) {
#pragma unroll
    for (int p = 0; p < 8; ++p) {
      int base = sr[p] * 33 + sk[p];
      As[base + 0] = st[p].x; As[base + 1] = st[p].y;
      As[base + 2] = st[p].z; As[base + 3] = st[p].w;
    }
    __syncthreads();
    if (kw + 1 < INCH / KW) {
#pragma unroll
      for (int p = 0; p < 8; ++p) {
        int gr = n0 + sr[p]; if (gr > NN - 1) gr = NN - 1;
        st[p] = *(const float4*)(Ab + (size_t)gr * INCH + (kw + 1) * KW + sk[p]);
      }
    }
    const float* Wk = W1T + (size_t)kw * KW * HC + col0;
#pragma unroll 4
    for (int kk = 0; kk < KW; ++kk) {
      float a = As[lrow * 33 + kk];
      const float* wr = Wk + (size_t)kk * HC;
#pragma unroll
      for (int c = 0; c < 64; ++c) acc[c] = fmaf(a, wr[c], acc[c]);
    }
    __syncthreads();
  }
  const float* bb = b1 + col0;
  float* op = xmid + (size_t)myrow * HC + col0;
#pragma unroll
  for (int c4 = 0; c4 < 16; ++c4) {
    float4 o;
    o.x = fmaxf(acc[c4 * 4 + 0] + bb[c4 * 4 + 0], 0.f);
    o.y = fmaxf(acc[c4 * 4 + 1] + bb[c4 * 4 + 1], 0.f);
    o.z = fmaxf(acc[c4 * 4 + 2] + bb[c4 * 4 + 2], 0.f);
    o.w = fmaxf(acc[c4 * 4 + 3] + bb[c4 * 4 + 3], 0.f);
    *(float4*)(op + c4 * 4) = o;
  }
}

// ---------------- gemm2: h2 = xmid@W2T + fused logits ----------------
__global__ __launch_bounds__(256) void k_gemm2(
    const float* __restrict__ xm, const float* __restrict__ W2T,
    const float* __restrict__ atts, const float* __restrict__ attd,
    float* __restrict__ h2, float* __restrict__ as2, float* __restrict__ ad2) {
  __shared__ float As[64 * 33];
  __shared__ float ps_sh[4][64], pd_sh[4][64];
  int tid = threadIdx.x;
  int lane = tid & 63, wv = tid >> 6;
  int n0 = blockIdx.x * 64;
  int col0 = wv * 16;
  int myrow = n0 + lane; if (myrow > NN - 1) myrow = NN - 1;

  float acc[16];
#pragma unroll
  for (int c = 0; c < 16; ++c) acc[c] = 0.f;

  float4 st[2];
  int sr[2], sk[2];
#pragma unroll
  for (int p = 0; p < 2; ++p) {
    int i = tid + p * 256;
    sr[p] = i >> 3; sk[p] = (i & 7) * 4;
    int gr = n0 + sr[p]; if (gr > NN - 1) gr = NN - 1;
    st[p] = *(const float4*)(xm + (size_t)gr * HC + sk[p]);
  }
  for (int kw = 0; kw < HC / KW; ++kw) {
#pragma unroll
    for (int p = 0; p < 2; ++p) {
      int base = sr[p] * 33 + sk[p];
      As[base + 0] = st[p].x; As[base + 1] = st[p].y;
      As[base + 2] = st[p].z; As[base + 3] = st[p].w;
    }
    __syncthreads();
    if (kw + 1 < HC / KW) {
#pragma unroll
      for (int p = 0; p < 2; ++p) {
        int gr = n0 + sr[p]; if (gr > NN - 1) gr = NN - 1;
        st[p] = *(const float4*)(xm + (size_t)gr * HC + (kw + 1) * KW + sk[p]);
      }
    }
    const float* Wk = W2T + (size_t)kw * KW * HIDC + col0;
#pragma unroll 4
    for (int kk = 0; kk < KW; ++kk) {
      float a = As[lane * 33 + kk];
      const float* wr = Wk + (size_t)kk * HIDC;
#pragma unroll
      for (int c = 0; c < 16; ++c) acc[c] = fmaf(a, wr[c], acc[c]);
    }
    __syncthreads();
  }
  const float* asl = atts + col0;
  const float* adl = attd + col0;
  float ps = 0.f, pd = 0.f;
  float* op = h2 + (size_t)myrow * HIDC + col0;
#pragma unroll
  for (int c4 = 0; c4 < 4; ++c4) {
    float4 o;
    o.x = acc[c4 * 4 + 0]; o.y = acc[c4 * 4 + 1]; o.z = acc[c4 * 4 + 2]; o.w = acc[c4 * 4 + 3];
    ps += o.x * asl[c4 * 4 + 0] + o.y * asl[c4 * 4 + 1] + o.z * asl[c4 * 4 + 2] + o.w * asl[c4 * 4 + 3];
    pd += o.x * adl[c4 * 4 + 0] + o.y * adl[c4 * 4 + 1] + o.z * adl[c4 * 4 + 2] + o.w * adl[c4 * 4 + 3];
    *(float4*)(op + c4 * 4) = o;
  }
  ps_sh[wv][lane] = ps; pd_sh[wv][lane] = pd;
  __syncthreads();
  if (wv == 0) {
    float s = ps_sh[0][lane] + ps_sh[1][lane] + ps_sh[2][lane] + ps_sh[3][lane];
    float d = pd_sh[0][lane] + pd_sh[1][lane] + pd_sh[2][lane] + pd_sh[3][lane];
    as2[myrow] = s; ad2[myrow] = d;
  }
}

// ---------------- Layer-2 fused softmax + aggregate (wave per node) ----------------
__global__ __launch_bounds__(256) void k_node2(
    const float* __restrict__ h2, const float* __restrict__ as2, const float* __restrict__ ad2,
    const int* __restrict__ rowstart, const int* __restrict__ csr,
    const float* __restrict__ b2, float* __restrict__ out) {
  int n = blockIdx.x * 4 + (threadIdx.x >> 6);
  if (n >= NN) return;
  int lane = threadIdx.x & 63;
  int rs = rowstart[n], re = rowstart[n + 1];
  float ad = ad2[n];
  float m = NEG_INF, z = 0.f, acc = 0.f;
  for (int base = rs; base < re; base += 64) {
    int cn = min(64, re - base);
    float e = NEG_INF;
    int s = 0;
    if (lane < cn) {
      s = csr[base + lane];
      float t = as2[s] + ad;
      e = (t > 0.f) ? t : SLOPE * t;
    }
    float cm = e;
#pragma unroll
    for (int off = 32; off; off >>= 1) cm = fmaxf(cm, __shfl_xor(cm, off));
    float mn = fmaxf(m, cm);
    float f = (m <= NEG_INF) ? 0.f : __expf(m - mn);
    float p = (lane < cn) ? __expf(e - mn) : 0.f;
    float zc = p;
#pragma unroll
    for (int off = 32; off; off >>= 1) zc += __shfl_xor(zc, off);
    z = z * f + zc;
    acc *= f;
    m = mn;
    for (int j = 0; j < cn; ++j) {
      float pj = __shfl(p, j);
      int sj = __shfl(s, j);
      acc = fmaf(pj, h2[(size_t)sj * HIDC + lane], acc);
    }
  }
  out[(size_t)n * HIDC + lane] = acc / (z + SMEPS) + b2[lane];
}

// ---------------- mean pool ----------------
__device__ inline int lowerb(const int* a, int n, int v) {
  int lo = 0, hi = n;
  while (lo < hi) { int mid = (lo + hi) >> 1; if (a[mid] < v) lo = mid + 1; else hi = mid; }
  return lo;
}

__global__ __launch_bounds__(256) void k_pool(const float* __restrict__ xm,
                                              const int* __restrict__ batch,
                                              float* __restrict__ out) {
  int g = blockIdx.x;
  int tid = threadIdx.x;
  int lo = lowerb(batch, NN, g);
  int hi = lowerb(batch, NN, g + 1);
  float inv = 1.f / fmaxf((float)(hi - lo), 1.f);
  int c = tid * 2;
  float sx = 0.f, sy = 0.f;
  int n = lo;
  for (; n + 4 <= hi; n += 4) {
    float2 v0 = *(const float2*)(xm + (size_t)(n + 0) * HC + c);
    float2 v1 = *(const float2*)(xm + (size_t)(n + 1) * HC + c);
    float2 v2 = *(const float2*)(xm + (size_t)(n + 2) * HC + c);
    float2 v3 = *(const float2*)(xm + (size_t)(n + 3) * HC + c);
    sx += (v0.x + v1.x) + (v2.x + v3.x);
    sy += (v0.y + v1.y) + (v2.y + v3.y);
  }
  for (; n < hi; ++n) {
    float2 v = *(const float2*)(xm + (size_t)n * HC + c);
    sx += v.x; sy += v.y;
  }
  out[(size_t)g * HC + c] = sx * inv;
  out[(size_t)g * HC + c + 1] = sy * inv;
}

extern "C" void kernel_launch(void* const* d_in, const int* in_sizes, int n_in,
                              void* d_out, int out_size, void* d_ws, size_t ws_size,
                              hipStream_t stream) {
  const float* x     = (const float*)d_in[0];
  const int*   ei    = (const int*)d_in[1];
  const int*   batch = (const int*)d_in[2];
  const float* W1    = (const float*)d_in[3];
  const float* atts1 = (const float*)d_in[4];
  const float* attd1 = (const float*)d_in[5];
  const float* b1    = (const float*)d_in[6];
  const float* W2    = (const float*)d_in[7];
  const float* atts2 = (const float*)d_in[8];
  const float* attd2 = (const float*)d_in[9];
  const float* b2    = (const float*)d_in[10];
  float* out = (float*)d_out;

  float* ws = (float*)d_ws;
  size_t off = 0;
  float* agg  = ws + off; off += (size_t)NH * NN * INCH;   // 20.48M floats
  float* xmid = ws + off; off += (size_t)NN * HC;          // 10.24M
  float* h2   = ws + off; off += (size_t)NN * HIDC;        // 1.28M
  float* al1  = ws + off; off += (size_t)NN * 16;
  float* as2  = ws + off; off += NN;
  float* ad2  = ws + off; off += NN;
  float* W1T  = ws + off; off += 512 * 128;
  float* W2T  = ws + off; off += 512 * 64;
  float* wB1  = ws + off; off += 2048;
  int* deg      = (int*)(ws + off); off += NN;
  int* wcur     = (int*)(ws + off); off += NN;
  int* rowstart = (int*)(ws + off); off += NN + 4;
  int* csr      = (int*)(ws + off); off += ETOT;

  hipMemsetAsync(deg, 0, sizeof(int) * 2 * NN, stream);
  k_prep<<<392, 256, 0, stream>>>(W1, W2, atts1, attd1, W1T, W2T, wB1);
  k_hist<<<(ETOT + 255) / 256, 256, 0, stream>>>(ei, deg);
  k_scan<<<1, 1024, 0, stream>>>(deg, rowstart);
  k_fill<<<(ETOT + 255) / 256, 256, 0, stream>>>(ei, rowstart, wcur, csr);

  k_logits1<<<79, 256, 0, stream>>>(x, wB1, al1);
  k_agg1<<<NN, 256, 0, stream>>>(x, al1, rowstart, csr, agg);
  k_gemm1h<<<79 * 8, 256, 0, stream>>>(agg, W1T, b1, xmid);
  k_pool<<<GG, 256, 0, stream>>>(xmid, batch, out);
  k_gemm2<<<313, 256, 0, stream>>>(xmid, W2T, atts2, attd2, h2, as2, ad2);
  k_node2<<<5000, 256, 0, stream>>>(h2, as2, ad2, rowstart, csr, b2, out + (size_t)GG * HC);
}

// Round 4
// 257.411 us; speedup vs baseline: 1.8838x; 1.7131x over previous
//
#include <hip/hip_runtime.h>
#include <math.h>

#define NN 20000
#define EE 320000
#define ETOT 340000
#define GG 64
#define INCH 128
#define HIDC 64
#define NH 8
#define HC 512            // NH*HIDC
#define SLOPE 0.2f
#define SMEPS 1e-16f

__device__ __forceinline__ float rlanef(float v, int l) {
  return __uint_as_float(__builtin_amdgcn_readlane(__float_as_uint(v), l));
}

// ---------------- CSR build ----------------
__global__ void k_hist(const int* __restrict__ ei, int* __restrict__ deg) {
  int i = blockIdx.x * 256 + threadIdx.x;
  if (i >= ETOT) return;
  int d = (i < EE) ? ei[EE + i] : (i - EE);
  atomicAdd(&deg[d], 1);
}

__global__ void k_scan(const int* __restrict__ deg, int* __restrict__ rowstart) {
  __shared__ int wsum[16];
  __shared__ int carry_sh;
  int tid = threadIdx.x;
  int lane = tid & 63, w = tid >> 6;
  if (tid == 0) { carry_sh = 0; rowstart[0] = 0; }
  __syncthreads();
  for (int base = 0; base < NN; base += 1024) {
    int v = (base + tid < NN) ? deg[base + tid] : 0;
    int s = v;
#pragma unroll
    for (int off = 1; off < 64; off <<= 1) {
      int t = __shfl_up(s, off);
      if (lane >= off) s += t;
    }
    if (lane == 63) wsum[w] = s;
    __syncthreads();
    if (w == 0 && lane < 16) {
      int t = wsum[lane];
#pragma unroll
      for (int off = 1; off < 16; off <<= 1) {
        int u = __shfl_up(t, off);
        if (lane >= off) t += u;
      }
      wsum[lane] = t;
    }
    __syncthreads();
    int waveoff = (w == 0) ? 0 : wsum[w - 1];
    int incl = s + waveoff + carry_sh;
    if (base + tid < NN) rowstart[base + tid + 1] = incl;
    __syncthreads();
    if (tid == 1023) carry_sh = incl;
    __syncthreads();
  }
}

__global__ void k_fill(const int* __restrict__ ei, const int* __restrict__ rowstart,
                       int* __restrict__ wcur, int* __restrict__ csr) {
  int i = blockIdx.x * 256 + threadIdx.x;
  if (i >= ETOT) return;
  int s, d;
  if (i < EE) { s = ei[i]; d = ei[EE + i]; } else { s = i - EE; d = s; }
  int pos = rowstart[d] + atomicAdd(&wcur[d], 1);
  csr[pos] = s;
}

// ---------------- weight prep: W1T[128][512], W2T[512][64], wB1[128][16] ----------------
__global__ void k_prep(const float* __restrict__ W1, const float* __restrict__ W2,
                       const float* __restrict__ as1, const float* __restrict__ ad1v,
                       float* __restrict__ W1T, float* __restrict__ W2T,
                       float* __restrict__ wB1) {
  int i = blockIdx.x * 256 + threadIdx.x;
  if (i < 512 * 128) {
    int k = i >> 9, o = i & 511;
    W1T[i] = W1[o * 128 + k];
  } else if (i < 512 * 128 + 512 * 64) {
    int j = i - 512 * 128;
    int k = j >> 6, c = j & 63;
    W2T[j] = W2[c * 512 + k];
  } else if (i < 512 * 128 + 512 * 64 + 2048) {
    int j = i - 512 * 128 - 512 * 64;   // j = k*16 + c
    int k = j >> 4, c = j & 15;
    int h = c & 7;
    const float* av = (c < 8) ? as1 : ad1v;
    float s = 0.f;
    for (int q = 0; q < 64; ++q) s += W1[(h * 64 + q) * 128 + k] * av[h * 64 + q];
    wB1[j] = s;
  }
}

// ---------------- logits1: al1[n][0..7]=x@wS, [8..15]=x@wD (4 threads / row) ------------
__global__ __launch_bounds__(256) void k_logits1(
    const float* __restrict__ x, const float* __restrict__ wB1,
    float* __restrict__ al1) {
  __shared__ float bs[128][16];
  int tid = threadIdx.x;
#pragma unroll
  for (int i = 0; i < 8; ++i) {
    int e = tid + i * 256;
    bs[e >> 4][e & 15] = wB1[e];
  }
  __syncthreads();
  int gt = blockIdx.x * 256 + tid;
  int r = gt >> 2; if (r > NN - 1) r = NN - 1;
  int q = gt & 3;
  const float* xp = x + (size_t)r * INCH;
  float acc[4] = {0.f, 0.f, 0.f, 0.f};
  for (int kq = 0; kq < 32; ++kq) {
    float4 a = *(const float4*)(xp + kq * 4);
    float av[4] = {a.x, a.y, a.z, a.w};
#pragma unroll
    for (int kk = 0; kk < 4; ++kk) {
      const float4 b = *(const float4*)&bs[kq * 4 + kk][q * 4];
      acc[0] = fmaf(av[kk], b.x, acc[0]);
      acc[1] = fmaf(av[kk], b.y, acc[1]);
      acc[2] = fmaf(av[kk], b.z, acc[2]);
      acc[3] = fmaf(av[kk], b.w, acc[3]);
    }
  }
  float4 o; o.x = acc[0]; o.y = acc[1]; o.z = acc[2]; o.w = acc[3];
  *(float4*)(al1 + (size_t)r * 16 + q * 4) = o;
}

// ---------------- agg1: wave/node, un-stabilized softmax, aggregate x -------------------
__global__ __launch_bounds__(256) void k_agg1(
    const float* __restrict__ x, const float* __restrict__ al1,
    const int* __restrict__ rowstart, const int* __restrict__ csr,
    float* __restrict__ agg) {
  int n = blockIdx.x * 4 + (threadIdx.x >> 6);
  int lane = threadIdx.x & 63;
  int rs = __builtin_amdgcn_readfirstlane(rowstart[n]);
  int re = __builtin_amdgcn_readfirstlane(rowstart[n + 1]);
  float4 ad0 = *(const float4*)(al1 + (size_t)n * 16 + 8);
  float4 ad1 = *(const float4*)(al1 + (size_t)n * 16 + 12);
  float zp[NH] = {};
  float accx[NH] = {}, accy[NH] = {};
  for (int base = rs; base < re; base += 64) {
    int cn = min(64, re - base);
    int idx = base + ((lane < cn) ? lane : 0);
    int s = csr[idx];
    float4 a0 = *(const float4*)(al1 + (size_t)s * 16);
    float4 a1 = *(const float4*)(al1 + (size_t)s * 16 + 4);
    float e[8] = {a0.x + ad0.x, a0.y + ad0.y, a0.z + ad0.z, a0.w + ad0.w,
                  a1.x + ad1.x, a1.y + ad1.y, a1.z + ad1.z, a1.w + ad1.w};
    float p[8];
#pragma unroll
    for (int h = 0; h < 8; ++h) {
      float t = e[h]; t = (t > 0.f) ? t : SLOPE * t;
      float pv = __expf(t);
      pv = (lane < cn) ? pv : 0.f;
      p[h] = pv;
      zp[h] += pv;
    }
    for (int j = 0; j < cn; ++j) {
      int sj = __builtin_amdgcn_readlane(s, j);
      const float2 xv = *(const float2*)(x + (size_t)sj * INCH + lane * 2);
#pragma unroll
      for (int h = 0; h < 8; ++h) {
        float pj = rlanef(p[h], j);
        accx[h] = fmaf(pj, xv.x, accx[h]);
        accy[h] = fmaf(pj, xv.y, accy[h]);
      }
    }
  }
#pragma unroll
  for (int h = 0; h < 8; ++h) {
    float z = zp[h];
#pragma unroll
    for (int off = 32; off; off >>= 1) z += __shfl_xor(z, off);
    float inv = 1.f / (z + SMEPS);
    float2 o; o.x = accx[h] * inv; o.y = accy[h] * inv;
    *(float2*)(agg + (size_t)h * NN * INCH + (size_t)n * INCH + lane * 2) = o;
  }
}

// ---------------- gemm1h: xmid[:, h*64..] = relu(agg_h @ W1T_h + b1) --------------------
__global__ __launch_bounds__(256) void k_gemm1h(
    const float* __restrict__ agg, const float* __restrict__ W1T,
    const float* __restrict__ b1, float* __restrict__ xmid) {
  __shared__ float As[32][257];
  __shared__ float Bs[32][64];
  int tid = threadIdx.x;
  int head = blockIdx.x & 7;
  int nb = blockIdx.x >> 3;
  int n0 = nb * 256;
  const float* Ab = agg + (size_t)head * NN * INCH;
  int tx = tid & 7, ty = tid >> 3;
  float acc[8][8] = {};
  for (int w = 0; w < 4; ++w) {
    __syncthreads();
#pragma unroll
    for (int i = 0; i < 8; ++i) {
      int e = tid + i * 256;
      int rr = e >> 3, kq = (e & 7) * 4;
      int gr = n0 + rr; if (gr > NN - 1) gr = NN - 1;
      float4 a = *(const float4*)(Ab + (size_t)gr * INCH + w * 32 + kq);
      As[kq + 0][rr] = a.x; As[kq + 1][rr] = a.y; As[kq + 2][rr] = a.z; As[kq + 3][rr] = a.w;
    }
#pragma unroll
    for (int i = 0; i < 2; ++i) {
      int e = tid + i * 256;
      int k = e >> 4, c4 = (e & 15) * 4;
      *(float4*)&Bs[k][c4] = *(const float4*)(W1T + (size_t)(w * 32 + k) * HC + head * 64 + c4);
    }
    __syncthreads();
#pragma unroll 2
    for (int kk = 0; kk < 32; ++kk) {
      float a[8], b[8];
      *(float4*)&a[0] = *(const float4*)&As[kk][ty * 8];
      *(float4*)&a[4] = *(const float4*)&As[kk][ty * 8 + 4];
      *(float4*)&b[0] = *(const float4*)&Bs[kk][tx * 8];
      *(float4*)&b[4] = *(const float4*)&Bs[kk][tx * 8 + 4];
#pragma unroll
      for (int i = 0; i < 8; ++i)
#pragma unroll
        for (int j = 0; j < 8; ++j) acc[i][j] = fmaf(a[i], b[j], acc[i][j]);
    }
  }
  const float* bb = b1 + head * 64 + tx * 8;
#pragma unroll
  for (int i = 0; i < 8; ++i) {
    int n = n0 + ty * 8 + i; if (n > NN - 1) n = NN - 1;
    float* op = xmid + (size_t)n * HC + head * 64 + tx * 8;
    float4 o0, o1;
    o0.x = fmaxf(acc[i][0] + bb[0], 0.f);
    o0.y = fmaxf(acc[i][1] + bb[1], 0.f);
    o0.z = fmaxf(acc[i][2] + bb[2], 0.f);
    o0.w = fmaxf(acc[i][3] + bb[3], 0.f);
    o1.x = fmaxf(acc[i][4] + bb[4], 0.f);
    o1.y = fmaxf(acc[i][5] + bb[5], 0.f);
    o1.z = fmaxf(acc[i][6] + bb[6], 0.f);
    o1.w = fmaxf(acc[i][7] + bb[7], 0.f);
    *(float4*)op = o0; *(float4*)(op + 4) = o1;
  }
}

// ---------------- gemm2: h2p[ksp] = xmid @ W2T (K-chunk 128), 128x64 tile, 8x4 micro ----
// grid = 4*157; blockIdx.x = ksp*157 + nb
__global__ __launch_bounds__(256) void k_gemm2(
    const float* __restrict__ xm, const float* __restrict__ W2T,
    float* __restrict__ h2p) {
  __shared__ float As[64][129];
  __shared__ float Bs[64][64];
  int tid = threadIdx.x;
  int nb = blockIdx.x % 157;
  int ksp = blockIdx.x / 157;
  int n0 = nb * 128;
  int koff = ksp * 128;
  int tx = tid & 15, ty = tid >> 4;
  float acc[8][4] = {};
  for (int w = 0; w < 2; ++w) {
    __syncthreads();
#pragma unroll
    for (int i = 0; i < 8; ++i) {
      int e = tid + i * 256;
      int rr = e >> 4, kq = (e & 15) * 4;
      int gr = n0 + rr; if (gr > NN - 1) gr = NN - 1;
      float4 a = *(const float4*)(xm + (size_t)gr * HC + koff + w * 64 + kq);
      As[kq + 0][rr] = a.x; As[kq + 1][rr] = a.y; As[kq + 2][rr] = a.z; As[kq + 3][rr] = a.w;
    }
#pragma unroll
    for (int i = 0; i < 4; ++i) {
      int e = tid + i * 256;
      int k = e >> 4, c4 = (e & 15) * 4;
      *(float4*)&Bs[k][c4] = *(const float4*)(W2T + (size_t)(koff + w * 64 + k) * HIDC + c4);
    }
    __syncthreads();
#pragma unroll 2
    for (int kk = 0; kk < 64; ++kk) {
      float a[8], b[4];
      *(float4*)&a[0] = *(const float4*)&As[kk][ty * 8];
      *(float4*)&a[4] = *(const float4*)&As[kk][ty * 8 + 4];
      *(float4*)&b[0] = *(const float4*)&Bs[kk][tx * 4];
#pragma unroll
      for (int i = 0; i < 8; ++i)
#pragma unroll
        for (int j = 0; j < 4; ++j) acc[i][j] = fmaf(a[i], b[j], acc[i][j]);
    }
  }
  float* hp = h2p + (size_t)ksp * NN * HIDC;
#pragma unroll
  for (int i = 0; i < 8; ++i) {
    int n = n0 + ty * 8 + i; if (n > NN - 1) n = NN - 1;
    float4 o; o.x = acc[i][0]; o.y = acc[i][1]; o.z = acc[i][2]; o.w = acc[i][3];
    *(float4*)(hp + (size_t)n * HIDC + tx * 4) = o;
  }
}

// ---------------- reduce k-split partials + layer-2 logits ------------------------------
__global__ __launch_bounds__(256) void k_red(
    const float* __restrict__ h2p, const float* __restrict__ atts, const float* __restrict__ attd,
    float* __restrict__ h2, float* __restrict__ as2, float* __restrict__ ad2) {
  int n = blockIdx.x * 4 + (threadIdx.x >> 6);
  int c = threadIdx.x & 63;
  size_t o = (size_t)n * HIDC + c;
  const size_t sp = (size_t)NN * HIDC;
  float v = h2p[o] + h2p[sp + o] + h2p[2 * sp + o] + h2p[3 * sp + o];
  h2[o] = v;
  float ps = v * atts[c], pd = v * attd[c];
#pragma unroll
  for (int off = 32; off; off >>= 1) { ps += __shfl_xor(ps, off); pd += __shfl_xor(pd, off); }
  if (c == 0) { as2[n] = ps; ad2[n] = pd; }
}

// ---------------- node2: wave/node, un-stabilized softmax over h2 -----------------------
__global__ __launch_bounds__(256) void k_node2(
    const float* __restrict__ h2, const float* __restrict__ as2, const float* __restrict__ ad2,
    const int* __restrict__ rowstart, const int* __restrict__ csr,
    const float* __restrict__ b2, float* __restrict__ out) {
  int n = blockIdx.x * 4 + (threadIdx.x >> 6);
  int lane = threadIdx.x & 63;
  int rs = __builtin_amdgcn_readfirstlane(rowstart[n]);
  int re = __builtin_amdgcn_readfirstlane(rowstart[n + 1]);
  float ad = ad2[n];
  float zp = 0.f, acc = 0.f;
  for (int base = rs; base < re; base += 64) {
    int cn = min(64, re - base);
    int idx = base + ((lane < cn) ? lane : 0);
    int s = csr[idx];
    float t = as2[s] + ad;
    t = (t > 0.f) ? t : SLOPE * t;
    float p = (lane < cn) ? __expf(t) : 0.f;
    zp += p;
    for (int j = 0; j < cn; ++j) {
      int sj = __builtin_amdgcn_readlane(s, j);
      float pj = rlanef(p, j);
      acc = fmaf(pj, h2[(size_t)sj * HIDC + lane], acc);
    }
  }
  float z = zp;
#pragma unroll
  for (int off = 32; off; off >>= 1) z += __shfl_xor(z, off);
  out[(size_t)n * HIDC + lane] = acc / (z + SMEPS) + b2[lane];
}

// ---------------- mean pool ----------------
__device__ inline int lowerb(const int* a, int n, int v) {
  int lo = 0, hi = n;
  while (lo < hi) { int mid = (lo + hi) >> 1; if (a[mid] < v) lo = mid + 1; else hi = mid; }
  return lo;
}

__global__ __launch_bounds__(256) void k_pool(const float* __restrict__ xm,
                                              const int* __restrict__ batch,
                                              float* __restrict__ out) {
  int g = blockIdx.x;
  int tid = threadIdx.x;
  int lo = lowerb(batch, NN, g);
  int hi = lowerb(batch, NN, g + 1);
  float inv = 1.f / fmaxf((float)(hi - lo), 1.f);
  int c = tid * 2;
  float sx = 0.f, sy = 0.f;
  int n = lo;
  for (; n + 4 <= hi; n += 4) {
    float2 v0 = *(const float2*)(xm + (size_t)(n + 0) * HC + c);
    float2 v1 = *(const float2*)(xm + (size_t)(n + 1) * HC + c);
    float2 v2 = *(const float2*)(xm + (size_t)(n + 2) * HC + c);
    float2 v3 = *(const float2*)(xm + (size_t)(n + 3) * HC + c);
    sx += (v0.x + v1.x) + (v2.x + v3.x);
    sy += (v0.y + v1.y) + (v2.y + v3.y);
  }
  for (; n < hi; ++n) {
    float2 v = *(const float2*)(xm + (size_t)n * HC + c);
    sx += v.x; sy += v.y;
  }
  out[(size_t)g * HC + c] = sx * inv;
  out[(size_t)g * HC + c + 1] = sy * inv;
}

extern "C" void kernel_launch(void* const* d_in, const int* in_sizes, int n_in,
                              void* d_out, int out_size, void* d_ws, size_t ws_size,
                              hipStream_t stream) {
  const float* x     = (const float*)d_in[0];
  const int*   ei    = (const int*)d_in[1];
  const int*   batch = (const int*)d_in[2];
  const float* W1    = (const float*)d_in[3];
  const float* atts1 = (const float*)d_in[4];
  const float* attd1 = (const float*)d_in[5];
  const float* b1    = (const float*)d_in[6];
  const float* W2    = (const float*)d_in[7];
  const float* atts2 = (const float*)d_in[8];
  const float* attd2 = (const float*)d_in[9];
  const float* b2    = (const float*)d_in[10];
  float* out = (float*)d_out;

  float* ws = (float*)d_ws;
  size_t off = 0;
  float* agg  = ws + off; off += (size_t)NH * NN * INCH;   // 20.48M floats; reused as h2p
  float* xmid = ws + off; off += (size_t)NN * HC;          // 10.24M
  float* h2   = ws + off; off += (size_t)NN * HIDC;        // 1.28M
  float* al1  = ws + off; off += (size_t)NN * 16;
  float* as2  = ws + off; off += NN;
  float* ad2  = ws + off; off += NN;
  float* W1T  = ws + off; off += 512 * 128;
  float* W2T  = ws + off; off += 512 * 64;
  float* wB1  = ws + off; off += 2048;
  int* deg      = (int*)(ws + off); off += NN;
  int* wcur     = (int*)(ws + off); off += NN;
  int* rowstart = (int*)(ws + off); off += NN + 4;
  int* csr      = (int*)(ws + off); off += ETOT;
  float* h2p = agg;   // alias: agg dead after k_gemm1h; h2p live from k_gemm2 on

  hipMemsetAsync(deg, 0, sizeof(int) * 2 * NN, stream);
  k_prep<<<392, 256, 0, stream>>>(W1, W2, atts1, attd1, W1T, W2T, wB1);
  k_hist<<<(ETOT + 255) / 256, 256, 0, stream>>>(ei, deg);
  k_scan<<<1, 1024, 0, stream>>>(deg, rowstart);
  k_fill<<<(ETOT + 255) / 256, 256, 0, stream>>>(ei, rowstart, wcur, csr);

  k_logits1<<<313, 256, 0, stream>>>(x, wB1, al1);
  k_agg1<<<5000, 256, 0, stream>>>(x, al1, rowstart, csr, agg);
  k_gemm1h<<<79 * 8, 256, 0, stream>>>(agg, W1T, b1, xmid);
  k_pool<<<GG, 256, 0, stream>>>(xmid, batch, out);
  k_gemm2<<<4 * 157, 256, 0, stream>>>(xmid, W2T, h2p);
  k_red<<<5000, 256, 0, stream>>>(h2p, atts2, attd2, h2, as2, ad2);
  k_node2<<<5000, 256, 0, stream>>>(h2, as2, ad2, rowstart, csr, b2, out + (size_t)GG * HC);
}

// Round 5
// 219.717 us; speedup vs baseline: 2.2070x; 1.1716x over previous
//
#include <hip/hip_runtime.h>
#include <math.h>

#define NN 20000
#define EE 320000
#define ETOT 340000
#define GG 64
#define INCH 128
#define HIDC 64
#define NH 8
#define HC 512            // NH*HIDC
#define SLOPE 0.2f
#define SMEPS 1e-16f

typedef unsigned short u16;
typedef unsigned int u32;
typedef __attribute__((ext_vector_type(8))) short bf16x8;
typedef __attribute__((ext_vector_type(4))) float f32x4;

__device__ __forceinline__ float rlanef(float v, int l) {
  return __uint_as_float(__builtin_amdgcn_readlane(__float_as_uint(v), l));
}
__device__ __forceinline__ u16 f2bf(float f) {   // round-to-nearest-even
  u32 x = __float_as_uint(f);
  x += 0x7FFFu + ((x >> 16) & 1u);
  return (u16)(x >> 16);
}

// ---------------- CSR build ----------------
__global__ void k_hist(const int* __restrict__ ei, int* __restrict__ deg) {
  int i = blockIdx.x * 256 + threadIdx.x;
  if (i >= ETOT) return;
  int d = (i < EE) ? ei[EE + i] : (i - EE);
  atomicAdd(&deg[d], 1);
}

__global__ void k_scan(const int* __restrict__ deg, int* __restrict__ rowstart) {
  __shared__ int wsum[16];
  __shared__ int carry_sh;
  int tid = threadIdx.x;
  int lane = tid & 63, w = tid >> 6;
  if (tid == 0) { carry_sh = 0; rowstart[0] = 0; }
  __syncthreads();
  for (int base = 0; base < NN; base += 1024) {
    int v = (base + tid < NN) ? deg[base + tid] : 0;
    int s = v;
#pragma unroll
    for (int off = 1; off < 64; off <<= 1) {
      int t = __shfl_up(s, off);
      if (lane >= off) s += t;
    }
    if (lane == 63) wsum[w] = s;
    __syncthreads();
    if (w == 0 && lane < 16) {
      int t = wsum[lane];
#pragma unroll
      for (int off = 1; off < 16; off <<= 1) {
        int u = __shfl_up(t, off);
        if (lane >= off) t += u;
      }
      wsum[lane] = t;
    }
    __syncthreads();
    int waveoff = (w == 0) ? 0 : wsum[w - 1];
    int incl = s + waveoff + carry_sh;
    if (base + tid < NN) rowstart[base + tid + 1] = incl;
    __syncthreads();
    if (tid == 1023) carry_sh = incl;
    __syncthreads();
  }
}

__global__ void k_fill(const int* __restrict__ ei, const int* __restrict__ rowstart,
                       int* __restrict__ wcur, int* __restrict__ csr) {
  int i = blockIdx.x * 256 + threadIdx.x;
  if (i >= ETOT) return;
  int s, d;
  if (i < EE) { s = ei[i]; d = ei[EE + i]; } else { s = i - EE; d = s; }
  int pos = rowstart[d] + atomicAdd(&wcur[d], 1);
  csr[pos] = s;
}

// ---------------- prep: W1bf, W2bf (bf16 copies; [col][k] == B-frag layout), wB1 -------
__global__ void k_prep(const float* __restrict__ W1, const float* __restrict__ W2,
                       const float* __restrict__ as1, const float* __restrict__ ad1v,
                       u16* __restrict__ W1bf, u16* __restrict__ W2bf,
                       float* __restrict__ wB1) {
  int i = blockIdx.x * 256 + threadIdx.x;
  if (i < 65536) {
    W1bf[i] = f2bf(W1[i]);
  } else if (i < 65536 + 32768) {
    int j = i - 65536;
    W2bf[j] = f2bf(W2[j]);
  } else if (i < 65536 + 32768 + 2048) {
    int j = i - 65536 - 32768;   // j = k*16 + c
    int k = j >> 4, c = j & 15;
    int h = c & 7;
    const float* av = (c < 8) ? as1 : ad1v;
    float s = 0.f;
    for (int q = 0; q < 64; ++q) s += W1[(h * 64 + q) * 128 + k] * av[h * 64 + q];
    wB1[j] = s;
  }
}

// ---------------- logits1: al1[n][0..7]=x@wS, [8..15]=x@wD (4 threads / row) ------------
__global__ __launch_bounds__(256) void k_logits1(
    const float* __restrict__ x, const float* __restrict__ wB1,
    float* __restrict__ al1) {
  __shared__ float bs[128][16];
  int tid = threadIdx.x;
#pragma unroll
  for (int i = 0; i < 8; ++i) {
    int e = tid + i * 256;
    bs[e >> 4][e & 15] = wB1[e];
  }
  __syncthreads();
  int gt = blockIdx.x * 256 + tid;
  int r = gt >> 2; if (r > NN - 1) r = NN - 1;
  int q = gt & 3;
  const float* xp = x + (size_t)r * INCH;
  float acc[4] = {0.f, 0.f, 0.f, 0.f};
  for (int kq = 0; kq < 32; ++kq) {
    float4 a = *(const float4*)(xp + kq * 4);
    float av[4] = {a.x, a.y, a.z, a.w};
#pragma unroll
    for (int kk = 0; kk < 4; ++kk) {
      const float4 b = *(const float4*)&bs[kq * 4 + kk][q * 4];
      acc[0] = fmaf(av[kk], b.x, acc[0]);
      acc[1] = fmaf(av[kk], b.y, acc[1]);
      acc[2] = fmaf(av[kk], b.z, acc[2]);
      acc[3] = fmaf(av[kk], b.w, acc[3]);
    }
  }
  float4 o; o.x = acc[0]; o.y = acc[1]; o.z = acc[2]; o.w = acc[3];
  *(float4*)(al1 + (size_t)r * 16 + q * 4) = o;
}

// ---------------- agg1: wave/node softmax + aggregate x; output bf16 --------------------
__global__ __launch_bounds__(256) void k_agg1(
    const float* __restrict__ x, const float* __restrict__ al1,
    const int* __restrict__ rowstart, const int* __restrict__ csr,
    u16* __restrict__ aggbf) {
  int n = blockIdx.x * 4 + (threadIdx.x >> 6);
  int lane = threadIdx.x & 63;
  int rs = __builtin_amdgcn_readfirstlane(rowstart[n]);
  int re = __builtin_amdgcn_readfirstlane(rowstart[n + 1]);
  float4 ad0 = *(const float4*)(al1 + (size_t)n * 16 + 8);
  float4 ad1 = *(const float4*)(al1 + (size_t)n * 16 + 12);
  float zp[NH] = {};
  float accx[NH] = {}, accy[NH] = {};
  for (int base = rs; base < re; base += 64) {
    int cn = min(64, re - base);
    int idx = base + ((lane < cn) ? lane : 0);
    int s = csr[idx];
    float4 a0 = *(const float4*)(al1 + (size_t)s * 16);
    float4 a1 = *(const float4*)(al1 + (size_t)s * 16 + 4);
    float e[8] = {a0.x + ad0.x, a0.y + ad0.y, a0.z + ad0.z, a0.w + ad0.w,
                  a1.x + ad1.x, a1.y + ad1.y, a1.z + ad1.z, a1.w + ad1.w};
    float p[8];
#pragma unroll
    for (int h = 0; h < 8; ++h) {
      float t = e[h]; t = (t > 0.f) ? t : SLOPE * t;
      float pv = __expf(t);
      pv = (lane < cn) ? pv : 0.f;
      p[h] = pv;
      zp[h] += pv;
    }
    for (int j = 0; j < cn; ++j) {
      int sj = __builtin_amdgcn_readlane(s, j);
      const float2 xv = *(const float2*)(x + (size_t)sj * INCH + lane * 2);
#pragma unroll
      for (int h = 0; h < 8; ++h) {
        float pj = rlanef(p[h], j);
        accx[h] = fmaf(pj, xv.x, accx[h]);
        accy[h] = fmaf(pj, xv.y, accy[h]);
      }
    }
  }
#pragma unroll
  for (int h = 0; h < 8; ++h) {
    float z = zp[h];
#pragma unroll
    for (int off = 32; off; off >>= 1) z += __shfl_xor(z, off);
    float inv = 1.f / (z + SMEPS);
    u32 pk = ((u32)f2bf(accy[h] * inv) << 16) | (u32)f2bf(accx[h] * inv);
    *(u32*)(aggbf + (size_t)h * NN * INCH + (size_t)n * INCH + lane * 2) = pk;
  }
}

// ---------------- gemm1h: xmid[:, h*64..] = relu(agg_h @ W1_h^T + b1), MFMA bf16 --------
// block=256 (4 waves), wave = 16 rows x 64 cols, K=128. B frags in regs, A streamed.
__global__ __launch_bounds__(256) void k_gemm1h(
    const u16* __restrict__ aggbf, const u16* __restrict__ W1bf,
    const float* __restrict__ b1, float* __restrict__ xmid) {
  int tid = threadIdx.x;
  int head = blockIdx.x & 7;
  int nb = blockIdx.x >> 3;
  int w = tid >> 6, l = tid & 63;
  int li = l & 15, hi = l >> 4;
  const u16* Ab = aggbf + (size_t)head * NN * INCH;
  const u16* Bb = W1bf + (size_t)head * 64 * INCH;

  bf16x8 Bf[4][4];   // [ks][ct]: B[k][col], lane holds col=li, k=ks*32+hi*8..+8
#pragma unroll
  for (int ks = 0; ks < 4; ++ks)
#pragma unroll
    for (int ct = 0; ct < 4; ++ct)
      Bf[ks][ct] = *(const bf16x8*)(Bb + (size_t)(ct * 16 + li) * INCH + ks * 32 + hi * 8);

  int nA = nb * 64 + w * 16 + li; if (nA > NN - 1) nA = NN - 1;
  const u16* Ap = Ab + (size_t)nA * INCH + hi * 8;
  f32x4 acc[4] = {};
#pragma unroll
  for (int ks = 0; ks < 4; ++ks) {
    bf16x8 Af = *(const bf16x8*)(Ap + ks * 32);
#pragma unroll
    for (int ct = 0; ct < 4; ++ct)
      acc[ct] = __builtin_amdgcn_mfma_f32_16x16x32_bf16(Af, Bf[ks][ct], acc[ct], 0, 0, 0);
  }
  // C/D: col = lane&15 (within ct tile), row = (lane>>4)*4 + reg
#pragma unroll
  for (int ct = 0; ct < 4; ++ct) {
    float bb = b1[head * 64 + ct * 16 + li];
#pragma unroll
    for (int reg = 0; reg < 4; ++reg) {
      int r = nb * 64 + w * 16 + hi * 4 + reg; if (r > NN - 1) r = NN - 1;
      float v = fmaxf(acc[ct][reg] + bb, 0.f);
      xmid[(size_t)r * HC + head * 64 + ct * 16 + li] = v;
    }
  }
}

// ---------------- gemm2: h2 = xmid @ W2^T (MFMA bf16, K split over 4 waves) + logits ----
// block=256, block tile = 16 rows x 64 cols; wave w handles K window [w*128, w*128+128)
__global__ __launch_bounds__(256) void k_gemm2(
    const float* __restrict__ xm, const u16* __restrict__ W2bf,
    const float* __restrict__ atts, const float* __restrict__ attd,
    float* __restrict__ h2, float* __restrict__ as2, float* __restrict__ ad2) {
  __shared__ float red[4][16][65];
  int tid = threadIdx.x;
  int w = tid >> 6, l = tid & 63;
  int li = l & 15, hi = l >> 4;
  int brow = blockIdx.x * 16;     // 1250 blocks * 16 = 20000 exact

  bf16x8 Bf[4][4];
#pragma unroll
  for (int ksl = 0; ksl < 4; ++ksl)
#pragma unroll
    for (int ct = 0; ct < 4; ++ct)
      Bf[ksl][ct] = *(const bf16x8*)(W2bf + (size_t)(ct * 16 + li) * HC + w * 128 + ksl * 32 + hi * 8);

  const float* Ap = xm + (size_t)(brow + li) * HC + w * 128 + hi * 8;
  f32x4 acc[4] = {};
#pragma unroll
  for (int ksl = 0; ksl < 4; ++ksl) {
    float4 a0 = *(const float4*)(Ap + ksl * 32);
    float4 a1 = *(const float4*)(Ap + ksl * 32 + 4);
    bf16x8 Af;
    Af[0] = (short)f2bf(a0.x); Af[1] = (short)f2bf(a0.y);
    Af[2] = (short)f2bf(a0.z); Af[3] = (short)f2bf(a0.w);
    Af[4] = (short)f2bf(a1.x); Af[5] = (short)f2bf(a1.y);
    Af[6] = (short)f2bf(a1.z); Af[7] = (short)f2bf(a1.w);
#pragma unroll
    for (int ct = 0; ct < 4; ++ct)
      acc[ct] = __builtin_amdgcn_mfma_f32_16x16x32_bf16(Af, Bf[ksl][ct], acc[ct], 0, 0, 0);
  }
#pragma unroll
  for (int ct = 0; ct < 4; ++ct)
#pragma unroll
    for (int reg = 0; reg < 4; ++reg)
      red[w][hi * 4 + reg][ct * 16 + li] = acc[ct][reg];
  __syncthreads();

  int c = l;                       // wave w now handles rows {w, w+4, w+8, w+12}, col c
  float atv = atts[c], adv = attd[c];
  float vs[4], vd[4];
#pragma unroll
  for (int i = 0; i < 4; ++i) {
    int r = w + 4 * i;
    float v = red[0][r][c] + red[1][r][c] + red[2][r][c] + red[3][r][c];
    h2[(size_t)(brow + r) * HIDC + c] = v;
    vs[i] = v * atv; vd[i] = v * adv;
  }
#pragma unroll
  for (int off = 32; off; off >>= 1) {
#pragma unroll
    for (int i = 0; i < 4; ++i) { vs[i] += __shfl_xor(vs[i], off); vd[i] += __shfl_xor(vd[i], off); }
  }
  if (l == 0) {
#pragma unroll
    for (int i = 0; i < 4; ++i) {
      int n = brow + w + 4 * i;
      as2[n] = vs[i]; ad2[n] = vd[i];
    }
  }
}

// ---------------- node2: wave/node, un-stabilized softmax over h2 -----------------------
__global__ __launch_bounds__(256) void k_node2(
    const float* __restrict__ h2, const float* __restrict__ as2, const float* __restrict__ ad2,
    const int* __restrict__ rowstart, const int* __restrict__ csr,
    const float* __restrict__ b2, float* __restrict__ out) {
  int n = blockIdx.x * 4 + (threadIdx.x >> 6);
  int lane = threadIdx.x & 63;
  int rs = __builtin_amdgcn_readfirstlane(rowstart[n]);
  int re = __builtin_amdgcn_readfirstlane(rowstart[n + 1]);
  float ad = ad2[n];
  float zp = 0.f, acc = 0.f;
  for (int base = rs; base < re; base += 64) {
    int cn = min(64, re - base);
    int idx = base + ((lane < cn) ? lane : 0);
    int s = csr[idx];
    float t = as2[s] + ad;
    t = (t > 0.f) ? t : SLOPE * t;
    float p = (lane < cn) ? __expf(t) : 0.f;
    zp += p;
    for (int j = 0; j < cn; ++j) {
      int sj = __builtin_amdgcn_readlane(s, j);
      float pj = rlanef(p, j);
      acc = fmaf(pj, h2[(size_t)sj * HIDC + lane], acc);
    }
  }
  float z = zp;
#pragma unroll
  for (int off = 32; off; off >>= 1) z += __shfl_xor(z, off);
  out[(size_t)n * HIDC + lane] = acc / (z + SMEPS) + b2[lane];
}

// ---------------- mean pool ----------------
__device__ inline int lowerb(const int* a, int n, int v) {
  int lo = 0, hi = n;
  while (lo < hi) { int mid = (lo + hi) >> 1; if (a[mid] < v) lo = mid + 1; else hi = mid; }
  return lo;
}

__global__ __launch_bounds__(256) void k_pool(const float* __restrict__ xm,
                                              const int* __restrict__ batch,
                                              float* __restrict__ out) {
  int g = blockIdx.x;
  int tid = threadIdx.x;
  int lo = lowerb(batch, NN, g);
  int hi = lowerb(batch, NN, g + 1);
  float inv = 1.f / fmaxf((float)(hi - lo), 1.f);
  int c = tid * 2;
  float sx = 0.f, sy = 0.f;
  int n = lo;
  for (; n + 4 <= hi; n += 4) {
    float2 v0 = *(const float2*)(xm + (size_t)(n + 0) * HC + c);
    float2 v1 = *(const float2*)(xm + (size_t)(n + 1) * HC + c);
    float2 v2 = *(const float2*)(xm + (size_t)(n + 2) * HC + c);
    float2 v3 = *(const float2*)(xm + (size_t)(n + 3) * HC + c);
    sx += (v0.x + v1.x) + (v2.x + v3.x);
    sy += (v0.y + v1.y) + (v2.y + v3.y);
  }
  for (; n < hi; ++n) {
    float2 v = *(const float2*)(xm + (size_t)n * HC + c);
    sx += v.x; sy += v.y;
  }
  out[(size_t)g * HC + c] = sx * inv;
  out[(size_t)g * HC + c + 1] = sy * inv;
}

extern "C" void kernel_launch(void* const* d_in, const int* in_sizes, int n_in,
                              void* d_out, int out_size, void* d_ws, size_t ws_size,
                              hipStream_t stream) {
  const float* x     = (const float*)d_in[0];
  const int*   ei    = (const int*)d_in[1];
  const int*   batch = (const int*)d_in[2];
  const float* W1    = (const float*)d_in[3];
  const float* atts1 = (const float*)d_in[4];
  const float* attd1 = (const float*)d_in[5];
  const float* b1    = (const float*)d_in[6];
  const float* W2    = (const float*)d_in[7];
  const float* atts2 = (const float*)d_in[8];
  const float* attd2 = (const float*)d_in[9];
  const float* b2    = (const float*)d_in[10];
  float* out = (float*)d_out;

  float* ws = (float*)d_ws;
  size_t off = 0;
  u16*  aggbf = (u16*)(ws + off); off += (size_t)NH * NN * INCH / 2;  // bf16 [8][20000][128]
  float* xmid = ws + off; off += (size_t)NN * HC;                     // fp32 [20000][512]
  float* h2   = ws + off; off += (size_t)NN * HIDC;
  float* al1  = ws + off; off += (size_t)NN * 16;
  float* as2  = ws + off; off += NN;
  float* ad2  = ws + off; off += NN;
  u16*  W1bf  = (u16*)(ws + off); off += 65536 / 2;
  u16*  W2bf  = (u16*)(ws + off); off += 32768 / 2;
  float* wB1  = ws + off; off += 2048;
  int* deg      = (int*)(ws + off); off += NN;
  int* wcur     = (int*)(ws + off); off += NN;
  int* rowstart = (int*)(ws + off); off += NN + 4;
  int* csr      = (int*)(ws + off); off += ETOT;

  hipMemsetAsync(deg, 0, sizeof(int) * 2 * NN, stream);
  k_prep<<<393, 256, 0, stream>>>(W1, W2, atts1, attd1, W1bf, W2bf, wB1);
  k_hist<<<(ETOT + 255) / 256, 256, 0, stream>>>(ei, deg);
  k_scan<<<1, 1024, 0, stream>>>(deg, rowstart);
  k_fill<<<(ETOT + 255) / 256, 256, 0, stream>>>(ei, rowstart, wcur, csr);

  k_logits1<<<313, 256, 0, stream>>>(x, wB1, al1);
  k_agg1<<<5000, 256, 0, stream>>>(x, al1, rowstart, csr, aggbf);
  k_gemm1h<<<313 * 8, 256, 0, stream>>>(aggbf, W1bf, b1, xmid);
  k_pool<<<GG, 256, 0, stream>>>(xmid, batch, out);
  k_gemm2<<<1250, 256, 0, stream>>>(xmid, W2bf, atts2, attd2, h2, as2, ad2);
  k_node2<<<5000, 256, 0, stream>>>(h2, as2, ad2, rowstart, csr, b2, out + (size_t)GG * HC);
}